// Round 3
// baseline (1502830.664 us; speedup 1.0000x reference)
//
#include <hip/hip_runtime.h>
#include <hip/hip_bf16.h>
#include <math.h>

#define TT 512
#define BB 64
#define FF 256
#define HH 1024

// ---------------------------------------------------------------------------
// Transpose x[b][t][f] -> xT[t][f][b]. xT ALIASES d_out (dead until out_proj).
// ---------------------------------------------------------------------------
__global__ __launch_bounds__(256) void k_transpose_x(const float* __restrict__ x,
                                                     float* __restrict__ xT) {
    int t = blockIdx.x;
    for (int idx = threadIdx.x; idx < BB * FF; idx += 256) {
        int b = idx >> 8;
        int f = idx & 255;
        xT[((size_t)t * FF + f) * BB + b] = x[((size_t)b * TT + t) * FF + f];
    }
}

// ---------------------------------------------------------------------------
// Latency-tolerant fused LSTM step.
// Block = 16 weight rows (4 hidden units x 4 gates); wave = gate; lane = batch.
// Weights: staged global->LDS in 256-k chunks, double buffered; inner loop
//   reads them as wave-uniform broadcasts (ds_read, conflict-free).
// Activations: per-lane coalesced global loads, 4-deep register prefetch ring
//   (48 loads in flight) so L2 latency hides under the FMA stream.
// ---------------------------------------------------------------------------
template <typename AT>
__device__ __forceinline__ void gemm_part2(
    const AT* __restrict__ A,          // [Kpart][BB] activation operand
    int Cpart,                         // chunks in this part (Kpart/256)
    int acBase,                        // absolute chunk index of this part's first chunk
    int C1, int NC,                    // chunks in part1 / total chunks
    const float* __restrict__ W1, int K1,   // part1 weight matrix [4096][K1]
    const float* __restrict__ W2,            // part2 weight matrix [4096][1024]
    float sW[2][16][256], int& buf,
    int tid, int lane, int gate, int j0,
    float acc[4])
{
    const int totG = Cpart * 16;       // 16-k groups in this part
    float av[4][16];

    // preload A groups 0..2
    #pragma unroll
    for (int p = 0; p < 3; ++p) {
        #pragma unroll
        for (int u = 0; u < 16; ++u)
            av[p][u] = (float)A[(size_t)(p * 16 + u) * BB + lane];
    }

    for (int c = 0; c < Cpart; ++c) {
        // ---- issue next chunk's weight loads (absolute chunk ac+1) ----
        float4 tv[4];
        const int acn = acBase + c + 1;
        const bool haveNext = (acn < NC);
        if (haveNext) {
            const float* Wb; int str; int kb;
            if (acn < C1) { Wb = W1; str = K1;   kb = acn * 256; }
            else          { Wb = W2; str = 1024; kb = (acn - C1) * 256; }
            #pragma unroll
            for (int i = 0; i < 4; ++i) {
                int idx = tid + i * 256;           // 0..1023
                int r   = idx >> 6;                // 0..15 (wave-uniform)
                int kk  = (idx & 63) << 2;         // 0..252, lane-consecutive
                int grow = (r >> 2) * HH + j0 + (r & 3);
                tv[i] = *(const float4*)(Wb + (size_t)grow * str + kb + kk);
            }
        }

        // ---- compute this chunk (k = 0..255 local) ----
        #pragma unroll
        for (int g = 0; g < 16; ++g) {
            const int pf = c * 16 + g + 3;         // group to prefetch
            if (pf < totG) {
                #pragma unroll
                for (int u = 0; u < 16; ++u)
                    av[(g + 3) & 3][u] = (float)A[(size_t)(pf * 16 + u) * BB + lane];
            }
            #pragma unroll
            for (int u = 0; u < 16; ++u) {
                const float hv = av[g & 3][u];
                const int k = g * 16 + u;
                acc[0] = fmaf(sW[buf][gate * 4 + 0][k], hv, acc[0]);
                acc[1] = fmaf(sW[buf][gate * 4 + 1][k], hv, acc[1]);
                acc[2] = fmaf(sW[buf][gate * 4 + 2][k], hv, acc[2]);
                acc[3] = fmaf(sW[buf][gate * 4 + 3][k], hv, acc[3]);
            }
        }

        // ---- commit next chunk to the other LDS buffer ----
        if (haveNext) {
            #pragma unroll
            for (int i = 0; i < 4; ++i) {
                int idx = tid + i * 256;
                int r   = idx >> 6;
                int kk  = (idx & 63) << 2;
                *(float4*)(&sW[buf ^ 1][r][kk]) = tv[i];
            }
        }
        __syncthreads();
        if (haveNext) buf ^= 1;
    }
}

template <typename AT>
__global__ __launch_bounds__(256) void k_lstm_step(
    const AT* __restrict__ A1, int K1,            // [K1][BB] input operand
    const float* __restrict__ W1,                 // [4096][K1]
    const float* __restrict__ Hprev,              // [HH][BB] fp32
    const float* __restrict__ W2,                 // [4096][HH]
    const float* __restrict__ bias,               // [4H]
    float* __restrict__ Hout,                     // [HH][BB] fp32
    __hip_bfloat16* __restrict__ HoutB,           // optional bf16 copy (or null)
    float* __restrict__ Cbuf)                     // [HH][BB] fp32
{
    __shared__ float sW[2][16][256];   // 32 KB double-buffered weight chunks
    __shared__ float gs[4][4][BB];     // 4 KB gate exchange

    const int tid  = threadIdx.x;
    const int lane = tid & 63;
    const int gate = __builtin_amdgcn_readfirstlane(tid >> 6);  // 0..3
    const int j0   = blockIdx.x * 4;

    const int C1 = K1 >> 8;            // chunks in part 1 (1 or 4)
    const int NC = C1 + (HH >> 8);     // + 4 recurrent chunks

    float acc[4];
    #pragma unroll
    for (int rr = 0; rr < 4; ++rr)
        acc[rr] = bias[gate * HH + j0 + rr];

    // ---- prologue: stage chunk 0 (from W1) ----
    {
        #pragma unroll
        for (int i = 0; i < 4; ++i) {
            int idx = tid + i * 256;
            int r   = idx >> 6;
            int kk  = (idx & 63) << 2;
            int grow = (r >> 2) * HH + j0 + (r & 3);
            float4 v = *(const float4*)(W1 + (size_t)grow * K1 + kk);
            *(float4*)(&sW[0][r][kk]) = v;
        }
    }
    __syncthreads();
    int buf = 0;

    // part 1: input projection (A1 @ W1^T)
    gemm_part2<AT>(A1, C1, 0, C1, NC, W1, K1, W2, sW, buf,
                   tid, lane, gate, j0, acc);
    // part 2: recurrence (Hprev @ W2^T)
    gemm_part2<float>(Hprev, HH >> 8, C1, C1, NC, W1, K1, W2, sW, buf,
                      tid, lane, gate, j0, acc);

    gs[gate][0][lane] = acc[0];
    gs[gate][1][lane] = acc[1];
    gs[gate][2][lane] = acc[2];
    gs[gate][3][lane] = acc[3];
    __syncthreads();

    {
        int jj = tid >> 6;
        int b  = tid & 63;
        float iv = gs[0][jj][b];
        float fv = gs[1][jj][b];
        float gv = gs[2][jj][b];
        float ov = gs[3][jj][b];
        iv = 1.0f / (1.0f + __expf(-iv));
        fv = 1.0f / (1.0f + __expf(-fv));
        gv = tanhf(gv);
        ov = 1.0f / (1.0f + __expf(-ov));
        size_t idx = (size_t)(j0 + jj) * BB + b;
        float c  = Cbuf[idx];
        float cn = fv * c + iv * gv;
        Cbuf[idx] = cn;
        float hn = ov * tanhf(cn);
        Hout[idx] = hn;
        if (HoutB) HoutB[idx] = (__hip_bfloat16)hn;
    }
}

// ---------------------------------------------------------------------------
// Output projection for one chunk of C timesteps starting at t0.
// ---------------------------------------------------------------------------
__global__ __launch_bounds__(256) void k_out_proj(
    const float* __restrict__ chunk,  // [C][HH][BB]
    const float* __restrict__ Wout,   // [FF][HH]
    const float* __restrict__ bout,   // [FF]
    float* __restrict__ out,          // [BB][TT][FF]
    int t0)
{
    int tl = blockIdx.x;
    int t  = t0 + tl;
    int fg = blockIdx.y;
    const int lane = threadIdx.x & 63;
    const int wv   = __builtin_amdgcn_readfirstlane(threadIdx.x >> 6);
    const int f0   = fg * 64 + wv * 16;
    const float* a = chunk + (size_t)tl * HH * BB;

    float acc[16];
    #pragma unroll
    for (int i = 0; i < 16; ++i) acc[i] = bout[f0 + i];

    for (int k = 0; k < HH; k += 4) {
        #pragma unroll
        for (int u = 0; u < 4; ++u) {
            float hv = a[(size_t)(k + u) * BB + lane];
            #pragma unroll
            for (int i = 0; i < 16; ++i)
                acc[i] = fmaf(Wout[(size_t)(f0 + i) * HH + k + u], hv, acc[i]);
        }
    }

    float* op = out + ((size_t)lane * TT + t) * FF + f0;
    #pragma unroll
    for (int i = 0; i < 16; i += 4) {
        float4 v = make_float4(acc[i], acc[i + 1], acc[i + 2], acc[i + 3]);
        *(float4*)(op + i) = v;
    }
}

// ---------------------------------------------------------------------------
extern "C" void kernel_launch(void* const* d_in, const int* in_sizes, int n_in,
                              void* d_out, int out_size, void* d_ws, size_t ws_size,
                              hipStream_t stream) {
    const float* x     = (const float*)d_in[0];
    const float* Wih_e = (const float*)d_in[1];
    const float* Whh_e = (const float*)d_in[2];
    const float* b_e   = (const float*)d_in[3];
    const float* Wih_d = (const float*)d_in[4];
    const float* Whh_d = (const float*)d_in[5];
    const float* b_d   = (const float*)d_in[6];
    const float* Wout  = (const float*)d_in[7];
    const float* bout  = (const float*)d_in[8];
    float* out = (float*)d_out;

    const size_t SF   = (size_t)HH * BB;     // 65536 elements per state
    const size_t encF = (size_t)TT * SF;

    float* xT = (float*)d_out;               // scratch alias; dead before out_proj

    // bf16 encoder-state tier (proven: ws_size >= needB(some C))
    int C = 64;
    {
        auto needB = [&](int c) {
            return encF * sizeof(__hip_bfloat16) + ((size_t)c * SF + 3 * SF) * sizeof(float);
        };
        if      (ws_size >= needB(64)) C = 64;
        else if (ws_size >= needB(32)) C = 32;
        else if (ws_size >= needB(16)) C = 16;
        else                           C = 8;
    }

    __hip_bfloat16* encB = (__hip_bfloat16*)d_ws;
    float* chunk = (float*)(encB + encF);
    float* hA    = chunk + (size_t)C * SF;
    float* hB    = hA + SF;
    float* cbuf  = hB + SF;
    hipMemsetAsync(hA,   0, SF * sizeof(float), stream);
    hipMemsetAsync(cbuf, 0, SF * sizeof(float), stream);

    k_transpose_x<<<TT, 256, 0, stream>>>(x, xT);

    float* hbuf[2] = { hA, hB };
    for (int t = 0; t < TT; ++t) {
        const float* hprev = hbuf[t & 1];
        float*       hout  = hbuf[(t + 1) & 1];
        k_lstm_step<float><<<HH / 4, 256, 0, stream>>>(
            xT + (size_t)t * FF * BB, FF, Wih_e, hprev, Whh_e, b_e,
            hout, encB + (size_t)t * SF, cbuf);
    }
    // final encoder h is in hbuf[0] == hA (TT even); c_T already in cbuf
    for (int t = 0; t < TT; ++t) {
        int l = t % C;
        const float* hprev = (t == 0) ? hA
                           : (l == 0) ? chunk + (size_t)(C - 1) * SF
                                      : chunk + (size_t)(l - 1) * SF;
        k_lstm_step<__hip_bfloat16><<<HH / 4, 256, 0, stream>>>(
            encB + (size_t)t * SF, HH, Wih_d, hprev, Whh_d, b_d,
            chunk + (size_t)l * SF, (__hip_bfloat16*)nullptr, cbuf);
        if (l == C - 1)
            k_out_proj<<<dim3(C, 4), 256, 0, stream>>>(chunk, Wout, bout, out,
                                                       t - (C - 1));
    }
}

// Round 4
// 17301.047 us; speedup vs baseline: 86.8636x; 86.8636x over previous
//
#include <hip/hip_runtime.h>
#include <math.h>

#define TT 512
#define BB 64
#define FF 256
#define HH 1024

typedef __attribute__((ext_vector_type(8))) short short8;
typedef __attribute__((ext_vector_type(4))) float f32x4;

__device__ __forceinline__ unsigned short f2bf(float f) {
    unsigned u = __float_as_uint(f);
    u += 0x7FFFu + ((u >> 16) & 1u);   // RNE (finite inputs only)
    return (unsigned short)(u >> 16);
}

// ---------------------------------------------------------------------------
// x[b][t][f] fp32 -> xB[t][b][f] bf16 (batch-major per step). xB lives in
// d_out (dead until out_proj, which runs strictly after the encoder).
// ---------------------------------------------------------------------------
__global__ __launch_bounds__(256) void k_cast_x(const float* __restrict__ x,
                                                unsigned short* __restrict__ xB) {
    int t = blockIdx.x;
    #pragma unroll
    for (int i = 0; i < 16; ++i) {
        int id = threadIdx.x + i * 256;       // 0..4095
        int b  = id >> 6;                     // 0..63
        int f4 = (id & 63) << 2;              // 0..252
        float4 v = *(const float4*)(x + ((size_t)b * TT + t) * FF + f4);
        ushort4 o;
        o.x = f2bf(v.x); o.y = f2bf(v.y); o.z = f2bf(v.z); o.w = f2bf(v.w);
        *(ushort4*)(xB + ((size_t)t * BB + b) * FF + f4) = o;
    }
}

// fp32 -> bf16 weight copy (n4 = element count / 4)
__global__ __launch_bounds__(256) void k_wcast(const float* __restrict__ in,
                                               unsigned short* __restrict__ out,
                                               int n4) {
    int stride = gridDim.x * 256;
    for (int i = blockIdx.x * 256 + threadIdx.x; i < n4; i += stride) {
        float4 v = ((const float4*)in)[i];
        ushort4 o;
        o.x = f2bf(v.x); o.y = f2bf(v.y); o.z = f2bf(v.z); o.w = f2bf(v.w);
        ((ushort4*)out)[i] = o;
    }
}

// ---------------------------------------------------------------------------
// One K-segment of the gate GEMM for one wave:
//   acc[m][n] += sum_k W[rowmap(m)][k] * A[b0+n][k]   via mfma 16x16x32 bf16
// a-frag: lane holds W[rowmap(lane&15)][q*8+j]; b-frag: A[b0+(lane&15)][q*8+j].
// WB=true: W already bf16. WB=false: fp32 W, convert in-regs.
// ---------------------------------------------------------------------------
template <bool WB>
__device__ __forceinline__ void seg(const unsigned short* __restrict__ ap0,
                                    const void* __restrict__ Wv,
                                    size_t woff, int nch, f32x4& acc) {
    const unsigned short* ap = ap0;
    if (WB) {
        const unsigned short* wp = (const unsigned short*)Wv + woff;
        #pragma unroll 4
        for (int c = 0; c < nch; ++c) {
            short8 av = *(const short8*)ap;
            short8 wv = *(const short8*)wp;
            acc = __builtin_amdgcn_mfma_f32_16x16x32_bf16(wv, av, acc, 0, 0, 0);
            ap += 32; wp += 32;
        }
    } else {
        const float* wp = (const float*)Wv + woff;
        #pragma unroll 2
        for (int c = 0; c < nch; ++c) {
            float4 wa = *(const float4*)wp;
            float4 wb = *(const float4*)(wp + 4);
            short8 av = *(const short8*)ap;
            short8 wv;
            wv[0] = (short)f2bf(wa.x); wv[1] = (short)f2bf(wa.y);
            wv[2] = (short)f2bf(wa.z); wv[3] = (short)f2bf(wa.w);
            wv[4] = (short)f2bf(wb.x); wv[5] = (short)f2bf(wb.y);
            wv[6] = (short)f2bf(wb.z); wv[7] = (short)f2bf(wb.w);
            acc = __builtin_amdgcn_mfma_f32_16x16x32_bf16(wv, av, acc, 0, 0, 0);
            ap += 32; wp += 32;
        }
    }
}

// ---------------------------------------------------------------------------
// Fused LSTM step (MFMA). Grid 256 x 256. Block = hidden units j0..j0+3
// (16 gate rows); wave w = batch tile b0=w*16. rowmap(m)=(m&3)*HH+j0+(m>>2)
// => lane(q,n) ends holding gates i,f,g,o (acc[0..3]) of unit j0+q, batch
// b0+n. Elementwise fully in-registers; no LDS, no barriers.
// ---------------------------------------------------------------------------
template <bool WB>
__global__ __launch_bounds__(256) void k_step(
    const unsigned short* __restrict__ A1, const void* __restrict__ W1, int K1,
    const unsigned short* __restrict__ A2, const void* __restrict__ W2, int K2,
    const float* __restrict__ bias,
    float* __restrict__ Cbuf,                 // [HH][BB] fp32 (persistent c)
    unsigned short* __restrict__ hOut,        // [BB][HH] bf16 (next-step A)
    float* __restrict__ chunkOut)             // [HH][BB] fp32 or null
{
    const int tid  = threadIdx.x;
    const int lane = tid & 63;
    const int w    = tid >> 6;
    const int q    = lane >> 4;
    const int n    = lane & 15;
    const int j0   = blockIdx.x * 4;
    const int rrow = (n & 3) * HH + j0 + (n >> 2);  // a-frag W row (mA = n)

    f32x4 acc = {0.f, 0.f, 0.f, 0.f};

    seg<WB>(A1 + (size_t)(w * 16 + n) * K1 + q * 8, W1,
            (size_t)rrow * K1 + q * 8, K1 >> 5, acc);
    if (K2)
        seg<WB>(A2 + (size_t)(w * 16 + n) * HH + q * 8, W2,
                (size_t)rrow * HH + q * 8, HH >> 5, acc);

    const int u = j0 + q;
    const int b = w * 16 + n;
    float pi = acc[0] + bias[u];
    float pf = acc[1] + bias[HH + u];
    float pg = acc[2] + bias[2 * HH + u];
    float po = acc[3] + bias[3 * HH + u];
    float iv = 1.f / (1.f + __expf(-pi));
    float fv = 1.f / (1.f + __expf(-pf));
    float gv = tanhf(pg);
    float ov = 1.f / (1.f + __expf(-po));
    size_t cix = (size_t)u * BB + b;
    float c  = Cbuf[cix];
    float cn = fv * c + iv * gv;
    Cbuf[cix] = cn;
    float hn = ov * tanhf(cn);
    hOut[(size_t)b * HH + u] = f2bf(hn);
    if (chunkOut) chunkOut[cix] = hn;
}

// ---------------------------------------------------------------------------
// Output projection for one chunk of C timesteps (round-2 proven kernel).
// ---------------------------------------------------------------------------
__global__ __launch_bounds__(256) void k_out_proj(
    const float* __restrict__ chunk,  // [C][HH][BB]
    const float* __restrict__ Wout,   // [FF][HH]
    const float* __restrict__ bout,   // [FF]
    float* __restrict__ out,          // [BB][TT][FF]
    int t0)
{
    int tl = blockIdx.x;
    int t  = t0 + tl;
    int fg = blockIdx.y;
    const int lane = threadIdx.x & 63;
    const int wv   = __builtin_amdgcn_readfirstlane(threadIdx.x >> 6);
    const int f0   = fg * 64 + wv * 16;
    const float* a = chunk + (size_t)tl * HH * BB;

    float acc[16];
    #pragma unroll
    for (int i = 0; i < 16; ++i) acc[i] = bout[f0 + i];

    for (int k = 0; k < HH; k += 4) {
        #pragma unroll
        for (int u = 0; u < 4; ++u) {
            float hv = a[(size_t)(k + u) * BB + lane];
            #pragma unroll
            for (int i = 0; i < 16; ++i)
                acc[i] = fmaf(Wout[(size_t)(f0 + i) * HH + k + u], hv, acc[i]);
        }
    }

    float* op = out + ((size_t)lane * TT + t) * FF + f0;
    #pragma unroll
    for (int i = 0; i < 16; i += 4) {
        float4 v = make_float4(acc[i], acc[i + 1], acc[i + 2], acc[i + 3]);
        *(float4*)(op + i) = v;
    }
}

// ---------------------------------------------------------------------------
extern "C" void kernel_launch(void* const* d_in, const int* in_sizes, int n_in,
                              void* d_out, int out_size, void* d_ws, size_t ws_size,
                              hipStream_t stream) {
    const float* x     = (const float*)d_in[0];
    const float* Wih_e = (const float*)d_in[1];
    const float* Whh_e = (const float*)d_in[2];
    const float* b_e   = (const float*)d_in[3];
    const float* Wih_d = (const float*)d_in[4];
    const float* Whh_d = (const float*)d_in[5];
    const float* b_d   = (const float*)d_in[6];
    const float* Wout  = (const float*)d_in[7];
    const float* bout  = (const float*)d_in[8];
    float* out = (float*)d_out;

    const size_t SB = (size_t)BB * HH;            // 65536 elems per state

    unsigned short* xB = (unsigned short*)d_out;  // [TT][BB][FF] bf16, 16.8MB

    // ---- workspace carve-up (tiered on ws_size; min tier = 69.7MB) ----
    char* p = (char*)d_ws;
    unsigned short* encB  = (unsigned short*)p; p += (size_t)TT * SB * 2; // 67.1MB
    unsigned short* dech0 = (unsigned short*)p; p += SB * 2;
    unsigned short* dech1 = (unsigned short*)p; p += SB * 2;
    float* cbuf = (float*)p; p += SB * 4;
    size_t used  = (size_t)(p - (char*)d_ws);
    size_t avail = ws_size > used ? ws_size - used : 0;

    const size_t WE_B = ((size_t)4 * HH * FF + (size_t)4 * HH * HH) * 2; // 10.5MB
    const size_t WD_B = ((size_t)4 * HH * HH) * 2 * 2;                   // 16.8MB
    const size_t CH8  = (size_t)8 * SB * 4;                              //  2.1MB

    bool wbAll = (avail >= WE_B + WD_B + CH8);
    bool wbEnc = wbAll || (avail >= WE_B + CH8);

    unsigned short *WihEb = 0, *WhhEb = 0, *WihDb = 0, *WhhDb = 0;
    if (wbEnc) {
        WihEb = (unsigned short*)p; p += (size_t)4 * HH * FF * 2;
        WhhEb = (unsigned short*)p; p += (size_t)4 * HH * HH * 2;
        avail -= WE_B;
    }
    if (wbAll) {
        WihDb = (unsigned short*)p; p += (size_t)4 * HH * HH * 2;
        WhhDb = (unsigned short*)p; p += (size_t)4 * HH * HH * 2;
        avail -= WD_B;
    }
    int C = 8;
    if      (avail >= (size_t)64 * SB * 4) C = 64;
    else if (avail >= (size_t)32 * SB * 4) C = 32;
    else if (avail >= (size_t)16 * SB * 4) C = 16;
    float* chunk = (float*)p;

    hipMemsetAsync(cbuf, 0, SB * 4, stream);
    k_cast_x<<<TT, 256, 0, stream>>>(x, xB);
    if (wbEnc) {
        k_wcast<<<1024, 256, 0, stream>>>(Wih_e, WihEb, 4 * HH * FF / 4);
        k_wcast<<<1024, 256, 0, stream>>>(Whh_e, WhhEb, 4 * HH * HH / 4);
    }
    if (wbAll) {
        k_wcast<<<1024, 256, 0, stream>>>(Wih_d, WihDb, 4 * HH * HH / 4);
        k_wcast<<<1024, 256, 0, stream>>>(Whh_d, WhhDb, 4 * HH * HH / 4);
    }

    // ---- encoder: h0 = 0 handled via K2=0 at t=0 (skip recurrent segment) ----
    for (int t = 0; t < TT; ++t) {
        const unsigned short* A1 = xB + (size_t)t * BB * FF;
        const unsigned short* A2 = t ? encB + (size_t)(t - 1) * SB : (unsigned short*)0;
        unsigned short* hOut = encB + (size_t)t * SB;
        if (wbEnc)
            k_step<true><<<256, 256, 0, stream>>>(A1, WihEb, FF, A2, WhhEb,
                t ? HH : 0, b_e, cbuf, hOut, (float*)0);
        else
            k_step<false><<<256, 256, 0, stream>>>(A1, Wih_e, FF, A2, Whh_e,
                t ? HH : 0, b_e, cbuf, hOut, (float*)0);
    }

    // ---- decoder: h0 = enc h_T (encB[TT-1]), c continues in cbuf ----
    for (int t = 0; t < TT; ++t) {
        const unsigned short* A1 = encB + (size_t)t * SB;
        const unsigned short* A2 = (t == 0) ? encB + (size_t)(TT - 1) * SB
                                            : ((t & 1) ? dech1 : dech0);
        unsigned short* hOut = ((t + 1) & 1) ? dech1 : dech0;
        int l = t & (C - 1);
        float* ch = chunk + (size_t)l * SB;
        if (wbAll)
            k_step<true><<<256, 256, 0, stream>>>(A1, WihDb, HH, A2, WhhDb, HH,
                                                  b_d, cbuf, hOut, ch);
        else
            k_step<false><<<256, 256, 0, stream>>>(A1, Wih_d, HH, A2, Whh_d, HH,
                                                   b_d, cbuf, hOut, ch);
        if (l == C - 1)
            k_out_proj<<<dim3(C, 4), 256, 0, stream>>>(chunk, Wout, bout, out,
                                                       t - (C - 1));
    }
}

// Round 5
// 11273.151 us; speedup vs baseline: 133.3106x; 1.5347x over previous
//
#include <hip/hip_runtime.h>
#include <math.h>

#define TT 512
#define BB 64
#define FF 256
#define HH 1024

typedef __attribute__((ext_vector_type(8))) short short8;
typedef __attribute__((ext_vector_type(4))) float f32x4;

__device__ __forceinline__ unsigned short f2bf(float f) {
    unsigned u = __float_as_uint(f);
    u += 0x7FFFu + ((u >> 16) & 1u);   // RNE (finite inputs only)
    return (unsigned short)(u >> 16);
}

// ---------------------------------------------------------------------------
// x[b][t][f] fp32 -> xB[t][b][f] bf16 (batch-major per step). xB lives in
// d_out (dead until out_proj).
// ---------------------------------------------------------------------------
__global__ __launch_bounds__(256) void k_cast_x(const float* __restrict__ x,
                                                unsigned short* __restrict__ xB) {
    int t = blockIdx.x;
    #pragma unroll
    for (int i = 0; i < 16; ++i) {
        int id = threadIdx.x + i * 256;
        int b  = id >> 6;
        int f4 = (id & 63) << 2;
        float4 v = *(const float4*)(x + ((size_t)b * TT + t) * FF + f4);
        ushort4 o;
        o.x = f2bf(v.x); o.y = f2bf(v.y); o.z = f2bf(v.z); o.w = f2bf(v.w);
        *(ushort4*)(xB + ((size_t)t * BB + b) * FF + f4) = o;
    }
}

__global__ __launch_bounds__(256) void k_wcast(const float* __restrict__ in,
                                               unsigned short* __restrict__ out,
                                               int n4) {
    int stride = gridDim.x * 256;
    for (int i = blockIdx.x * 256 + threadIdx.x; i < n4; i += stride) {
        float4 v = ((const float4*)in)[i];
        ushort4 o;
        o.x = f2bf(v.x); o.y = f2bf(v.y); o.z = f2bf(v.z); o.w = f2bf(v.w);
        ((ushort4*)out)[i] = o;
    }
}

// ---------------------------------------------------------------------------
// LDS-staged MFMA LSTM step. NCH = total 256-wide K-chunks (compile-time).
// Block: 4 hidden units (16 gate rows), 4 waves = 4 batch tiles of 16.
// sW[frag][lane] holds W fragments in MFMA order: frag g=(c,f), lane l ->
// W[rrow(l&15)][c*256 + f*32 + (l>>4)*8 ..+8]. ds_read_b128 lane-linear =
// conflict-free. A: per-lane 16B loads, 3-deep chunk ring (distance 2).
// Epilogue identical to the verified round-4 kernel.
// ---------------------------------------------------------------------------
template <int NCH>
__global__ __launch_bounds__(256) void k_step_lds(
    const unsigned short* __restrict__ A1, const unsigned short* __restrict__ W1, int K1,
    const unsigned short* __restrict__ A2, const unsigned short* __restrict__ W2, int K2,
    int C1,                                   // chunks in segment 1
    const float* __restrict__ bias,
    float* __restrict__ Cbuf,                 // [HH][BB] fp32 persistent c
    unsigned short* __restrict__ hOut,        // [BB][HH] bf16 next-step A
    float* __restrict__ chunkOut)             // [HH][BB] fp32 or null
{
    __shared__ short8 sW[NCH * 8 * 64];       // 8KB per chunk (dec: 64KB)

    const int tid  = threadIdx.x;
    const int lane = tid & 63;
    const int w    = tid >> 6;
    const int q    = lane >> 4;
    const int n    = lane & 15;
    const int j0   = blockIdx.x * 4;
    const int rrow = (n & 3) * HH + j0 + (n >> 2);

    short8 av[3][8];

    // A-chunk loader: 8 x 16B per lane, compile-time dst indices.
    auto aload = [&](short8* dst, int c) {
        const unsigned short* ap = (c < C1)
            ? A1 + (size_t)(w * 16 + n) * K1 + (size_t)c * 256
            : A2 + (size_t)(w * 16 + n) * K2 + (size_t)(c - C1) * 256;
        ap += q * 8;
        #pragma unroll
        for (int f = 0; f < 8; ++f) dst[f] = *(const short8*)(ap + f * 32);
    };

    // issue first A chunks before staging so they overlap it
    aload(av[0], 0);
    if (NCH > 1) aload(av[1], 1);

    // ---- stage W into LDS in fragment order (each wave 2*NCH frags) ----
    #pragma unroll
    for (int i = 0; i < 2 * NCH; ++i) {
        int g = i * 4 + w;                    // frag id 0..8*NCH-1
        int c = g >> 3, f = g & 7;
        const unsigned short* Wp; int Ks; int cl;
        if (c < C1) { Wp = W1; Ks = K1; cl = c; }
        else        { Wp = W2; Ks = K2; cl = c - C1; }
        sW[g * 64 + lane] =
            *(const short8*)(Wp + (size_t)rrow * Ks + (size_t)cl * 256 + f * 32 + q * 8);
    }
    __syncthreads();

    // ---- K loop: fully unrolled chunks, 2 interleaved accumulators ----
    f32x4 accA = {0.f, 0.f, 0.f, 0.f};
    f32x4 accB = {0.f, 0.f, 0.f, 0.f};
    #pragma unroll
    for (int c = 0; c < NCH; ++c) {
        if (c + 2 < NCH) aload(av[(c + 2) % 3], c + 2);
        const short8* cur = av[c % 3];
        #pragma unroll
        for (int f = 0; f < 8; ++f) {
            short8 wv = sW[(c * 8 + f) * 64 + lane];
            if (f & 1) accB = __builtin_amdgcn_mfma_f32_16x16x32_bf16(wv, cur[f], accB, 0, 0, 0);
            else       accA = __builtin_amdgcn_mfma_f32_16x16x32_bf16(wv, cur[f], accA, 0, 0, 0);
        }
    }
    f32x4 acc = accA + accB;

    // ---- epilogue (verified round-4 mapping) ----
    const int u = j0 + q;
    const int b = w * 16 + n;
    float pi = acc[0] + bias[u];
    float pf = acc[1] + bias[HH + u];
    float pg = acc[2] + bias[2 * HH + u];
    float po = acc[3] + bias[3 * HH + u];
    float iv = 1.f / (1.f + __expf(-pi));
    float fv = 1.f / (1.f + __expf(-pf));
    float gv = tanhf(pg);
    float ov = 1.f / (1.f + __expf(-po));
    size_t cix = (size_t)u * BB + b;
    float c  = Cbuf[cix];
    float cn = fv * c + iv * gv;
    Cbuf[cix] = cn;
    float hn = ov * tanhf(cn);
    hOut[(size_t)b * HH + u] = f2bf(hn);
    if (chunkOut) chunkOut[cix] = hn;
}

// ---------------------------------------------------------------------------
// Fallback step (fp32 weights in-kernel convert) — round-4 proven, used only
// when ws_size can't hold bf16 weight copies.
// ---------------------------------------------------------------------------
__device__ __forceinline__ void seg_f32(const unsigned short* __restrict__ ap0,
                                        const float* __restrict__ wp0,
                                        int nch, f32x4& acc) {
    const unsigned short* ap = ap0;
    const float* wp = wp0;
    #pragma unroll 2
    for (int c = 0; c < nch; ++c) {
        float4 wa = *(const float4*)wp;
        float4 wb = *(const float4*)(wp + 4);
        short8 av = *(const short8*)ap;
        short8 wv;
        wv[0] = (short)f2bf(wa.x); wv[1] = (short)f2bf(wa.y);
        wv[2] = (short)f2bf(wa.z); wv[3] = (short)f2bf(wa.w);
        wv[4] = (short)f2bf(wb.x); wv[5] = (short)f2bf(wb.y);
        wv[6] = (short)f2bf(wb.z); wv[7] = (short)f2bf(wb.w);
        acc = __builtin_amdgcn_mfma_f32_16x16x32_bf16(wv, av, acc, 0, 0, 0);
        ap += 32; wp += 32;
    }
}

__global__ __launch_bounds__(256) void k_step_f32w(
    const unsigned short* __restrict__ A1, const float* __restrict__ W1, int K1,
    const unsigned short* __restrict__ A2, const float* __restrict__ W2, int K2,
    const float* __restrict__ bias,
    float* __restrict__ Cbuf, unsigned short* __restrict__ hOut,
    float* __restrict__ chunkOut)
{
    const int tid  = threadIdx.x;
    const int lane = tid & 63;
    const int w    = tid >> 6;
    const int q    = lane >> 4;
    const int n    = lane & 15;
    const int j0   = blockIdx.x * 4;
    const int rrow = (n & 3) * HH + j0 + (n >> 2);

    f32x4 acc = {0.f, 0.f, 0.f, 0.f};
    seg_f32(A1 + (size_t)(w * 16 + n) * K1 + q * 8,
            W1 + (size_t)rrow * K1 + q * 8, K1 >> 5, acc);
    if (K2)
        seg_f32(A2 + (size_t)(w * 16 + n) * HH + q * 8,
                W2 + (size_t)rrow * HH + q * 8, HH >> 5, acc);

    const int u = j0 + q;
    const int b = w * 16 + n;
    float pi = acc[0] + bias[u];
    float pf = acc[1] + bias[HH + u];
    float pg = acc[2] + bias[2 * HH + u];
    float po = acc[3] + bias[3 * HH + u];
    float iv = 1.f / (1.f + __expf(-pi));
    float fv = 1.f / (1.f + __expf(-pf));
    float gv = tanhf(pg);
    float ov = 1.f / (1.f + __expf(-po));
    size_t cix = (size_t)u * BB + b;
    float c  = Cbuf[cix];
    float cn = fv * c + iv * gv;
    Cbuf[cix] = cn;
    float hn = ov * tanhf(cn);
    hOut[(size_t)b * HH + u] = f2bf(hn);
    if (chunkOut) chunkOut[cix] = hn;
}

// ---------------------------------------------------------------------------
// Output projection for one chunk of C timesteps (round-2 proven kernel).
// ---------------------------------------------------------------------------
__global__ __launch_bounds__(256) void k_out_proj(
    const float* __restrict__ chunk,  // [C][HH][BB]
    const float* __restrict__ Wout,   // [FF][HH]
    const float* __restrict__ bout,   // [FF]
    float* __restrict__ out,          // [BB][TT][FF]
    int t0)
{
    int tl = blockIdx.x;
    int t  = t0 + tl;
    int fg = blockIdx.y;
    const int lane = threadIdx.x & 63;
    const int wv   = __builtin_amdgcn_readfirstlane(threadIdx.x >> 6);
    const int f0   = fg * 64 + wv * 16;
    const float* a = chunk + (size_t)tl * HH * BB;

    float acc[16];
    #pragma unroll
    for (int i = 0; i < 16; ++i) acc[i] = bout[f0 + i];

    for (int k = 0; k < HH; k += 4) {
        #pragma unroll
        for (int u = 0; u < 4; ++u) {
            float hv = a[(size_t)(k + u) * BB + lane];
            #pragma unroll
            for (int i = 0; i < 16; ++i)
                acc[i] = fmaf(Wout[(size_t)(f0 + i) * HH + k + u], hv, acc[i]);
        }
    }

    float* op = out + ((size_t)lane * TT + t) * FF + f0;
    #pragma unroll
    for (int i = 0; i < 16; i += 4) {
        float4 v = make_float4(acc[i], acc[i + 1], acc[i + 2], acc[i + 3]);
        *(float4*)(op + i) = v;
    }
}

// ---------------------------------------------------------------------------
extern "C" void kernel_launch(void* const* d_in, const int* in_sizes, int n_in,
                              void* d_out, int out_size, void* d_ws, size_t ws_size,
                              hipStream_t stream) {
    const float* x     = (const float*)d_in[0];
    const float* Wih_e = (const float*)d_in[1];
    const float* Whh_e = (const float*)d_in[2];
    const float* b_e   = (const float*)d_in[3];
    const float* Wih_d = (const float*)d_in[4];
    const float* Whh_d = (const float*)d_in[5];
    const float* b_d   = (const float*)d_in[6];
    const float* Wout  = (const float*)d_in[7];
    const float* bout  = (const float*)d_in[8];
    float* out = (float*)d_out;

    const size_t SB = (size_t)BB * HH;            // 65536 elems per state

    unsigned short* xB = (unsigned short*)d_out;  // [TT][BB][FF] bf16

    // ---- workspace carve-up (same tiers as round 4) ----
    char* p = (char*)d_ws;
    unsigned short* encB  = (unsigned short*)p; p += (size_t)TT * SB * 2;
    unsigned short* dech0 = (unsigned short*)p; p += SB * 2;
    unsigned short* dech1 = (unsigned short*)p; p += SB * 2;
    float* cbuf = (float*)p; p += SB * 4;
    size_t used  = (size_t)(p - (char*)d_ws);
    size_t avail = ws_size > used ? ws_size - used : 0;

    const size_t WE_B = ((size_t)4 * HH * FF + (size_t)4 * HH * HH) * 2;
    const size_t WD_B = ((size_t)4 * HH * HH) * 2 * 2;
    const size_t CH8  = (size_t)8 * SB * 4;

    bool wbAll = (avail >= WE_B + WD_B + CH8);
    bool wbEnc = wbAll || (avail >= WE_B + CH8);

    unsigned short *WihEb = 0, *WhhEb = 0, *WihDb = 0, *WhhDb = 0;
    if (wbEnc) {
        WihEb = (unsigned short*)p; p += (size_t)4 * HH * FF * 2;
        WhhEb = (unsigned short*)p; p += (size_t)4 * HH * HH * 2;
        avail -= WE_B;
    }
    if (wbAll) {
        WihDb = (unsigned short*)p; p += (size_t)4 * HH * HH * 2;
        WhhDb = (unsigned short*)p; p += (size_t)4 * HH * HH * 2;
        avail -= WD_B;
    }
    int C = 8;
    if      (avail >= (size_t)64 * SB * 4) C = 64;
    else if (avail >= (size_t)32 * SB * 4) C = 32;
    else if (avail >= (size_t)16 * SB * 4) C = 16;
    float* chunk = (float*)p;

    hipMemsetAsync(cbuf, 0, SB * 4, stream);
    k_cast_x<<<TT, 256, 0, stream>>>(x, xB);
    if (wbEnc) {
        k_wcast<<<1024, 256, 0, stream>>>(Wih_e, WihEb, 4 * HH * FF / 4);
        k_wcast<<<1024, 256, 0, stream>>>(Whh_e, WhhEb, 4 * HH * HH / 4);
    }
    if (wbAll) {
        k_wcast<<<1024, 256, 0, stream>>>(Wih_d, WihDb, 4 * HH * HH / 4);
        k_wcast<<<1024, 256, 0, stream>>>(Whh_d, WhhDb, 4 * HH * HH / 4);
    }

    // ---- encoder ----
    for (int t = 0; t < TT; ++t) {
        const unsigned short* A1 = xB + (size_t)t * BB * FF;
        const unsigned short* A2 = t ? encB + (size_t)(t - 1) * SB : (unsigned short*)0;
        unsigned short* hOut = encB + (size_t)t * SB;
        if (wbEnc) {
            if (t == 0)
                k_step_lds<1><<<256, 256, 0, stream>>>(A1, WihEb, FF, A2, WhhEb, HH,
                                                       1, b_e, cbuf, hOut, (float*)0);
            else
                k_step_lds<5><<<256, 256, 0, stream>>>(A1, WihEb, FF, A2, WhhEb, HH,
                                                       1, b_e, cbuf, hOut, (float*)0);
        } else {
            k_step_f32w<<<256, 256, 0, stream>>>(A1, Wih_e, FF, A2, Whh_e,
                                                 t ? HH : 0, b_e, cbuf, hOut, (float*)0);
        }
    }

    // ---- decoder: h0 = enc h_T, c continues ----
    for (int t = 0; t < TT; ++t) {
        const unsigned short* A1 = encB + (size_t)t * SB;
        const unsigned short* A2 = (t == 0) ? encB + (size_t)(TT - 1) * SB
                                            : ((t & 1) ? dech1 : dech0);
        unsigned short* hOut = ((t + 1) & 1) ? dech1 : dech0;
        int l = t & (C - 1);
        float* ch = chunk + (size_t)l * SB;
        if (wbAll)
            k_step_lds<8><<<256, 256, 0, stream>>>(A1, WihDb, HH, A2, WhhDb, HH,
                                                   4, b_d, cbuf, hOut, ch);
        else
            k_step_f32w<<<256, 256, 0, stream>>>(A1, Wih_d, HH, A2, Whh_d, HH,
                                                 b_d, cbuf, hOut, ch);
        if (l == C - 1)
            k_out_proj<<<dim3(C, 4), 256, 0, stream>>>(chunk, Wout, bout, out,
                                                       t - (C - 1));
    }
}